// Round 13
// baseline (250.043 us; speedup 1.0000x reference)
//
#include <hip/hip_runtime.h>
#include <hip/hip_bf16.h>

// LSTM: B=4096, T=200, I=2, H=64, O=2
// grid = 256 blocks x 512 threads (8 waves, 2 waves/SIMD, 1 block/CU).
// BARRIER-FREE + 2 INDEPENDENT WAVES/SIMD: each wave owns TWO batch rows
// (block rows 2w, 2w+1) and computes the full 64-unit recurrence itself.
// 2048 independent waves; the only __syncthreads is the initial staging
// barrier. R12 lesson: barrier-free at 1 wave/SIMD exposes the in-wave
// chain (~900 cyc); with 2 independent waves/SIMD each wave's chain hides
// under its partner's ~400-cyc issue stream — no sync coupling at all.
//
// Static-index mappings:
//  * A'[p] = h[p>>3]: lane (g,c) loads A[row c][k=g*8+e] = h[c>>3][g*8+e];
//    D row 4g+reg -> batch row (4g+reg)>>3 = g>>1 for ALL regs -> extract
//    reg 0 only, statically.
//  * Gate-interleaved B-tiles: tile j <-> (gate m=j&3, unit-block ub=j>>2);
//    tile j column c = W_hh row 64m+16ub+c. All 16 tiles' reg-0 extracted
//    (ex[16], static); lane (g,c) selects its 8 (units 16(b+2q)+c, b=g&1,
//    q=0,1) via ternary of static elements -> 8 v_cndmask, no dyn indexing.
//  * Proj coeffs and h-write addresses absorb b at init (zero per-step cost).
// Per wave/step: 2 ds_read_b128 + 1 LDS float2 + 32 MFMA + 8 cndmask +
// 16 proj FMA + 2 fused ACT chains (10 exp + 4 rcp) + 2 ds_write_b16.
// hsh [wave][2][80]: reads 8 distinct 16B (8-way broadcast, 2-way alias);
// writes 2-way max. Conflict-free in practice.
// Activation algebra (gate scales folded into weights: i,f,o: -log2e,
// g: 2*log2e):
//   c' = (c*P + (Eg-1)(1+Ef)) * rcp(P*(1+Ef)),  P = (1+Ei)(Eg+1)
//   h  = (Ec-1) * rcp((1+Eo)(Ec+1)),            Ec = 2^(2*log2e*c)
// FC epilogue in-register: per-lane partials + __shfl_xor over 32-lane halves.

#define B_ 4096
#define T_ 200

typedef _Float16 half8 __attribute__((ext_vector_type(8)));
typedef float f32x4 __attribute__((ext_vector_type(4)));

#define K1f 1.4426950408889634f   // log2(e)
#define K2f 2.8853900817779268f   // 2*log2(e)

__global__ __launch_bounds__(512, 2) void lstm_kernel(
    const float* __restrict__ x,     // [4096][200][2]
    const float* __restrict__ W_ih,  // [256][2]
    const float* __restrict__ W_hh,  // [256][64]
    const float* __restrict__ b_ih,  // [256]
    const float* __restrict__ b_hh,  // [256]
    const float* __restrict__ W_fc,  // [2][64]
    const float* __restrict__ b_fc,  // [2]
    float* __restrict__ out)         // [4096][2]
{
    __shared__ float xs[16][404];       // x tile (float4-aligned rows)
    __shared__ _Float16 hsh[8][2][80];  // per-wave h: [wave][local row][unit], pad 64->80

    const int tid  = threadIdx.x;
    const int lane = tid & 63;
    const int w    = tid >> 6;      // wave 0..7 (independent 2-row LSTM)
    const int c    = lane & 15;     // B-col / unit low index
    const int g    = lane >> 4;     // lane group
    const int b    = g & 1;         // unit-block selector
    const int lr   = g >> 1;        // local batch row (0 or 1)
    const int r0   = blockIdx.x * 16;

    // ---- stage x tile (coalesced float4): 16 rows x 100 float4 ----
    for (int i4 = tid; i4 < 1600; i4 += 512) {
        const int row = i4 / 100;
        const int j4  = i4 - row * 100;
        reinterpret_cast<float4*>(&xs[row][0])[j4] =
            reinterpret_cast<const float4*>(x + (size_t)(r0 + row) * 400)[j4];
    }
    // ---- zero hsh: 8*2*80 f16 = 1280 f16 = 640 dwords ----
    for (int i = tid; i < 640; i += 512)
        reinterpret_cast<unsigned int*>(&hsh[0][0][0])[i] = 0u;
    __syncthreads();   // ONE-TIME staging barrier; none in the loop

    // ---- W_hh B-fragments (f16, gate-scaled), 16 tiles x 2 k-halves ----
    // B-frag (16x16x32): lane l -> col = l&15 (=c), k = (l>>4)*8 + e (=g*8+e)
    half8 bfrag[16][2];
    #pragma unroll
    for (int j = 0; j < 16; ++j) {
        const int m  = j & 3;           // gate: 0=i,1=f,2=g,3=o
        const int ub = j >> 2;          // unit block
        const float sc = (m == 2) ? K2f : -K1f;
        const int gr = 64 * m + 16 * ub + c;   // gate row (this lane's B col)
        #pragma unroll
        for (int kt = 0; kt < 2; ++kt) {
            const float* p = W_hh + gr * 64 + kt * 32 + g * 8;
            const float4 lo = reinterpret_cast<const float4*>(p)[0];
            const float4 hi = reinterpret_cast<const float4*>(p)[1];
            half8 f;
            f[0] = (_Float16)(lo.x * sc); f[1] = (_Float16)(lo.y * sc);
            f[2] = (_Float16)(lo.z * sc); f[3] = (_Float16)(lo.w * sc);
            f[4] = (_Float16)(hi.x * sc); f[5] = (_Float16)(hi.y * sc);
            f[6] = (_Float16)(hi.z * sc); f[7] = (_Float16)(hi.w * sc);
            bfrag[j][kt] = f;
        }
    }
    // ---- proj coeffs for this lane's two chains (s = b, b+2) ----
    float cw0[2][4], cw1[2][4], cbs[2][4];
    #pragma unroll
    for (int q = 0; q < 2; ++q) {
        const int s = b + 2 * q;
        #pragma unroll
        for (int m = 0; m < 4; ++m) {
            const float sc = (m == 2) ? K2f : -K1f;
            const int gr = 64 * m + 16 * s + c;
            cw0[q][m] = W_ih[gr * 2 + 0] * sc;
            cw1[q][m] = W_ih[gr * 2 + 1] * sc;
            cbs[q][m] = (b_ih[gr] + b_hh[gr]) * sc;
        }
    }

    const _Float16* hrd = &hsh[w][c >> 3][0];        // A-frag source row
    _Float16* hw0 = &hsh[w][lr][16 * b + c];         // chain 0 unit = 16b+c
    _Float16* hw1 = &hsh[w][lr][32 + 16 * b + c];    // chain 1 unit = 32+16b+c

    float cst0 = 0.f, cst1 = 0.f;    // cell states for the two owned units
    float hv0k = 0.f, hv1k = 0.f;    // last h values (for FC)

    for (int t = 0; t < T_; ++t) {
        // A-frag: lane (g,c) -> h[c>>3][g*8+e] (+32 for the second k-half)
        const half8 a0 = *reinterpret_cast<const half8*>(hrd + g * 8);
        const half8 a1 = *reinterpret_cast<const half8*>(hrd + 32 + g * 8);
        const float2 xv = *reinterpret_cast<const float2*>(&xs[2 * w + lr][2 * t]);

        // 16 tiles, extract reg 0 immediately (acc tuple dies per-tile)
        float ex[16];
        #pragma unroll
        for (int j = 0; j < 16; ++j) {
            f32x4 z = {0.f, 0.f, 0.f, 0.f};
            z = __builtin_amdgcn_mfma_f32_16x16x32_f16(a0, bfrag[j][0], z, 0, 0, 0);
            z = __builtin_amdgcn_mfma_f32_16x16x32_f16(a1, bfrag[j][1], z, 0, 0, 0);
            ex[j] = z[0];
        }

        // ---- chain q=0: s=b -> tiles 4b+m ; chain q=1: s=b+2 -> tiles 8+4b+m
        float pre0[4], pre1[4];
        #pragma unroll
        for (int m = 0; m < 4; ++m) {
            const float e0 = b ? ex[4 + m]  : ex[m];       // static both sides
            const float e1 = b ? ex[12 + m] : ex[8 + m];
            pre0[m] = fmaf(xv.y, cw1[0][m], fmaf(xv.x, cw0[0][m], cbs[0][m])) + e0;
            pre1[m] = fmaf(xv.y, cw1[1][m], fmaf(xv.x, cw0[1][m], cbs[1][m])) + e1;
        }

        #pragma unroll
        for (int q = 0; q < 2; ++q) {
            const float* pre = q ? pre1 : pre0;
            const float Ei = __builtin_amdgcn_exp2f(pre[0]);  // e^{-ip}
            const float Ef = __builtin_amdgcn_exp2f(pre[1]);  // e^{-fp}
            const float Eg = __builtin_amdgcn_exp2f(pre[2]);  // e^{2 gp}
            const float Eo = __builtin_amdgcn_exp2f(pre[3]);  // e^{-op}
            const float fEf = 1.0f + Ef;
            const float P   = (1.0f + Ei) * (Eg + 1.0f);
            const float r1  = __builtin_amdgcn_rcpf(P * fEf);
            float& cst = q ? cst1 : cst0;
            const float cv  = fmaf(cst, P, (Eg - 1.0f) * fEf) * r1;
            cst = cv;
            const float Ec = __builtin_amdgcn_exp2f(fminf(K2f * cv, 60.0f));
            const float r2 = __builtin_amdgcn_rcpf((1.0f + Eo) * (Ec + 1.0f));
            const float hv = (Ec - 1.0f) * r2;
            if (q) { hv1k = hv; *hw1 = (_Float16)hv; }
            else   { hv0k = hv; *hw0 = (_Float16)hv; }
            // next-iter a0/a1 read is same-wave; compiler inserts lgkmcnt
        }
    }

    // ---- FC epilogue, in-register ----
    float p0 = fmaf(W_fc[16 * b + c],      hv0k, W_fc[32 + 16 * b + c]      * hv1k);
    float p1 = fmaf(W_fc[64 + 16 * b + c], hv0k, W_fc[96 + 16 * b + c]      * hv1k);
    #pragma unroll
    for (int mk = 1; mk < 32; mk <<= 1) {   // reduce over the 32-lane row group
        p0 += __shfl_xor(p0, mk);
        p1 += __shfl_xor(p1, mk);
    }
    if ((lane & 31) == 0) {
        const int row = r0 + 2 * w + lr;
        out[row * 2 + 0] = p0 + b_fc[0];
        out[row * 2 + 1] = p1 + b_fc[1];
    }
}

extern "C" void kernel_launch(void* const* d_in, const int* in_sizes, int n_in,
                              void* d_out, int out_size, void* d_ws, size_t ws_size,
                              hipStream_t stream) {
    const float* x    = (const float*)d_in[0];
    const float* W_ih = (const float*)d_in[1];
    const float* W_hh = (const float*)d_in[2];
    const float* b_ih = (const float*)d_in[3];
    const float* b_hh = (const float*)d_in[4];
    const float* W_fc = (const float*)d_in[5];
    const float* b_fc = (const float*)d_in[6];
    float* out = (float*)d_out;

    lstm_kernel<<<B_ / 16, 512, 0, stream>>>(x, W_ih, W_hh, b_ih, b_hh, W_fc, b_fc, out);
}

// Round 14
// 142.890 us; speedup vs baseline: 1.7499x; 1.7499x over previous
//
#include <hip/hip_runtime.h>
#include <hip/hip_bf16.h>

// LSTM: B=4096, T=200, I=2, H=64, O=2
// grid = 256 blocks x 512 threads (8 waves, 2 waves/SIMD, 1 block/CU).
// R7 work decomposition + CROSS-BARRIER ACC PIPELINING.
// Block's 16 rows = two independent 8-row groups A (rows 0-7), B (rows 8-15).
// 400 intervals, one barrier each; interval 2t handles group A step t,
// interval 2t+1 group B step t. Per interval each wave:
//   1) ACT for the current group using acc computed LAST interval (the only
//      serial path: bar -> ACT(~170cyc) -> ds_write -> bar),
//   2) prefetch other group's h (written >=1 barrier ago, race-free) +
//      MFMA + x-proj folded in C -> acc for next interval (independent of
//      this interval's ACT -> retires under the barrier + next ACT),
//   3) __syncthreads.
// R8 failed because MFMA and its ACT sat in the SAME phase (chain paid 2x/step);
// here MFMA always has a full interval+barrier to retire.
// Mapping: wave w -> (wq = w&3: units 16wq+c), (hf = w>>2). Lane (g,c) owns
// (local row 2g+hf, unit 16wq+c). A-frag row map A'[p] = hG[((p>>1)+hf)&7]
// => D reg 0 of lane-group g = local row 2g+hf (STATIC). Coverage bijective:
// 8 waves x 64 lanes = 8 rows x 64 units. Other D regs unused (MFMA cheap).
// Activation algebra (gate scales folded into weights: i,f,o: -log2e,
// g: 2*log2e):
//   c' = (c*P + (Eg-1)(1+Ef)) * rcp(P*(1+Ef)),  P = (1+Ei)(Eg+1)
//   h  = (Ec-1) * rcp((1+Eo)(Ec+1)),            Ec = 2^(2*log2e*c)
// => 5 exp + 2 rcp per (row,unit); proj pre-added via MFMA C operand.

#define B_ 4096
#define T_ 200

typedef _Float16 half8 __attribute__((ext_vector_type(8)));
typedef float f32x4 __attribute__((ext_vector_type(4)));

#define K1f 1.4426950408889634f   // log2(e)
#define K2f 2.8853900817779268f   // 2*log2(e)

__global__ __launch_bounds__(512) void lstm_kernel(
    const float* __restrict__ x,     // [4096][200][2]
    const float* __restrict__ W_ih,  // [256][2]
    const float* __restrict__ W_hh,  // [256][64]
    const float* __restrict__ b_ih,  // [256]
    const float* __restrict__ b_hh,  // [256]
    const float* __restrict__ W_fc,  // [2][64]
    const float* __restrict__ b_fc,  // [2]
    float* __restrict__ out)         // [4096][2]
{
    __shared__ float xs[16][404];    // x tile (float4-aligned; cols 400..403 pad)
    __shared__ _Float16 hA[8][72];   // group A hidden state (local rows 0-7)
    __shared__ _Float16 hB[8][72];   // group B hidden state (local rows 0-7 = global 8-15)
    __shared__ float wfc[130];       // W_fc (128) + b_fc (2)

    const int tid  = threadIdx.x;
    const int lane = tid & 63;
    const int w    = tid >> 6;      // wave 0..7
    const int wq   = w & 3;         // unit quadrant
    const int hf   = w >> 2;        // row-half selector within the 8-row group
    const int c    = lane & 15;
    const int g    = lane >> 4;
    const int r0   = blockIdx.x * 16;

    // ---- stage x tile (coalesced float4): 16 rows x 100 float4 ----
    for (int i4 = tid; i4 < 1600; i4 += 512) {
        const int row = i4 / 100;
        const int j4  = i4 - row * 100;
        reinterpret_cast<float4*>(&xs[row][0])[j4] =
            reinterpret_cast<const float4*>(x + (size_t)(r0 + row) * 400)[j4];
    }
    // ---- zero xs pad cols 400..403 (dead t=200 prefetch) ----
    if (tid < 64) xs[tid >> 2][400 + (tid & 3)] = 0.f;
    // ---- zero hA and hB: 8*72 f16 = 576 f16 = 288 dwords each ----
    for (int i = tid; i < 288; i += 512)
        reinterpret_cast<unsigned int*>(&hA[0][0])[i] = 0u;
    for (int i = tid; i < 288; i += 512)
        reinterpret_cast<unsigned int*>(&hB[0][0])[i] = 0u;
    if (tid < 130) wfc[tid] = (tid < 128) ? W_fc[tid] : b_fc[tid - 128];

    // ---- W_hh B-fragments (f16, PRE-SCALED per gate) + x-proj coeffs ----
    // B-frag (16x16x32): lane l -> col = l&15 (=c), k = (l>>4)*8 + e
    half8 bfrag[4][2];
    float cw0[4], cw1[4], cbs[4];
    const int u = wq * 16 + c;             // hidden unit owned by this lane
    #pragma unroll
    for (int m = 0; m < 4; ++m) {          // gate: 0=i,1=f,2=g,3=o (PyTorch order)
        const float sc = (m == 2) ? K2f : -K1f;
        const int gr = m * 64 + u;
        cw0[m] = W_ih[gr * 2 + 0] * sc;
        cw1[m] = W_ih[gr * 2 + 1] * sc;
        cbs[m] = (b_ih[gr] + b_hh[gr]) * sc;
        #pragma unroll
        for (int kt = 0; kt < 2; ++kt) {
            const float* p = W_hh + gr * 64 + kt * 32 + g * 8;
            const float4 lo = reinterpret_cast<const float4*>(p)[0];
            const float4 hi = reinterpret_cast<const float4*>(p)[1];
            half8 f;
            f[0] = (_Float16)(lo.x * sc); f[1] = (_Float16)(lo.y * sc);
            f[2] = (_Float16)(lo.z * sc); f[3] = (_Float16)(lo.w * sc);
            f[4] = (_Float16)(hi.x * sc); f[5] = (_Float16)(hi.y * sc);
            f[6] = (_Float16)(hi.z * sc); f[7] = (_Float16)(hi.w * sc);
            bfrag[m][kt] = f;
        }
    }

    const int arow = ((c >> 1) + hf) & 7;  // A'[p] = hG[((p>>1)+hf)&7]
    const int rowL = 2 * g + hf;           // local row this lane activates
    const int g8   = g * 8;
    float cstA = 0.f, cstB = 0.f;
    float aA[4], aB[4];                    // pre-activation args (proj folded in)

    __syncthreads();                       // staging barrier

    // One activation chain: pre-act args already exp2-scaled.
    #define ACT(pre, cst, hvout)                                               \
        {                                                                      \
            const float Ei = __builtin_amdgcn_exp2f(pre[0]);                   \
            const float Ef = __builtin_amdgcn_exp2f(pre[1]);                   \
            const float Eg = __builtin_amdgcn_exp2f(pre[2]);                   \
            const float Eo = __builtin_amdgcn_exp2f(pre[3]);                   \
            const float fEf = 1.0f + Ef;                                       \
            const float P   = (1.0f + Ei) * (Eg + 1.0f);                       \
            const float r1  = __builtin_amdgcn_rcpf(P * fEf);                  \
            cst = fmaf(cst, P, (Eg - 1.0f) * fEf) * r1;                        \
            const float Ec = __builtin_amdgcn_exp2f(fminf(K2f * cst, 60.0f));  \
            const float r2 = __builtin_amdgcn_rcpf((1.0f + Eo) * (Ec + 1.0f)); \
            hvout = (Ec - 1.0f) * r2;                                          \
        }

    // Prefetch block: read hX, x-proj into C, MFMA -> aX (4 scalars, static)
    #define PREFETCH(hX, xrow, t, aX)                                          \
        {                                                                      \
            const half8 f0 = *reinterpret_cast<const half8*>(&hX[arow][g8]);   \
            const half8 f1 = *reinterpret_cast<const half8*>(&hX[arow][32 + g8]); \
            const float2 xv = *reinterpret_cast<const float2*>(&xs[xrow][2 * (t)]); \
            _Pragma("unroll")                                                  \
            for (int m = 0; m < 4; ++m) {                                      \
                const float pj = fmaf(xv.y, cw1[m], fmaf(xv.x, cw0[m], cbs[m])); \
                f32x4 z = {pj, pj, pj, pj};                                    \
                z = __builtin_amdgcn_mfma_f32_16x16x32_f16(f0, bfrag[m][0], z, 0, 0, 0); \
                z = __builtin_amdgcn_mfma_f32_16x16x32_f16(f1, bfrag[m][1], z, 0, 0, 0); \
                aX[m] = z[0];                                                  \
            }                                                                  \
        }

    // Prologue: aA for A's t=0 is pure proj (h(-1)=0); hB is zeroed so the
    // interval-0 prefetch MFMA yields proj-only for B's t=0 as well.
    {
        const float2 xv = *reinterpret_cast<const float2*>(&xs[rowL][0]);
        #pragma unroll
        for (int m = 0; m < 4; ++m)
            aA[m] = fmaf(xv.y, cw1[m], fmaf(xv.x, cw0[m], cbs[m]));
    }

    for (int t = 0; t < T_; ++t) {
        // ===== interval 2t: group A, step t =====
        {
            float hv;
            ACT(aA, cstA, hv);
            hA[rowL][u] = (_Float16)hv;
        }
        PREFETCH(hB, 8 + rowL, t, aB);        // acc for B step t (hB(t-1))
        __syncthreads();

        // ===== interval 2t+1: group B, step t =====
        {
            float hv;
            ACT(aB, cstB, hv);
            hB[rowL][u] = (_Float16)hv;
        }
        PREFETCH(hA, rowL, t + 1, aA);        // acc for A step t+1 (hA(t));
        __syncthreads();                      // t=199: reads zeroed pad, unused
    }

    // ---- FC epilogue: hA/hB hold h(t=199) for global rows 0-7 / 8-15 ----
    if (tid < 32) {
        const int r = tid & 15;
        const int o = tid >> 4;
        const _Float16* hsrc = (r < 8) ? &hA[r][0] : &hB[r - 8][0];
        float s = wfc[128 + o];
        #pragma unroll
        for (int k = 0; k < 64; ++k)
            s = fmaf(wfc[o * 64 + k], (float)hsrc[k], s);
        out[(size_t)(r0 + r) * 2 + o] = s;
    }
}

extern "C" void kernel_launch(void* const* d_in, const int* in_sizes, int n_in,
                              void* d_out, int out_size, void* d_ws, size_t ws_size,
                              hipStream_t stream) {
    const float* x    = (const float*)d_in[0];
    const float* W_ih = (const float*)d_in[1];
    const float* W_hh = (const float*)d_in[2];
    const float* b_ih = (const float*)d_in[3];
    const float* b_hh = (const float*)d_in[4];
    const float* W_fc = (const float*)d_in[5];
    const float* b_fc = (const float*)d_in[6];
    float* out = (float*)d_out;

    lstm_kernel<<<B_ / 16, 512, 0, stream>>>(x, W_ih, W_hh, b_ih, b_hh, W_fc, b_fc, out);
}

// Round 15
// 117.215 us; speedup vs baseline: 2.1332x; 1.2190x over previous
//
#include <hip/hip_runtime.h>
#include <hip/hip_bf16.h>

// LSTM: B=4096, T=200, I=2, H=64, O=2
// grid = 256 blocks x 512 threads (8 waves, 2 waves/SIMD, 1 block/CU).
// DECOUPLED GROUPS + LDS SPIN-SYNC (no s_barrier in the loop):
// Block's 16 rows = two INDEPENDENT 8-row LSTMs: group A (waves 0-3, rows
// 0-7), group B (waves 4-7, rows 8-15). Each group syncs only its own 4
// waves once per step via an LDS generation counter (fence -> lane-0
// atomicAdd -> spin with s_sleep). Groups are completely uncoupled, so the
// A-wave and B-wave sharing each SIMD can run at DIFFERENT steps: a one-time
// s_sleep(8) offsets group B by ~half a step, and thereafter each wave's
// serial chain (ds_read 120 -> MFMA 80 -> ACT 170 -> write -> sync) hides
// under its SIMD-partner's ~440-cyc issue stream. R3/R5/R7/R8/R11/R14 all
// phase-locked on block-wide s_barrier (idle 500-900/step); this removes
// the lock entirely. h is double-buffered per group (read t&1, write t&1^1)
// so no WAR race; spin target 4*(t+1) gives exact RAW ordering.
// Work mapping per group (R11-verified): wave quadrant wq=w&3 -> units
// [16wq,16wq+16). A'[p] = hG[p>>1] (rows duplicated x2): D reg 0 = local row
// 2g, D reg 2 = local row 2g+1 (STATIC). C preloaded {p0,p0,p1,p1} with the
// matching x-projections (gate-scaled).
// Activation algebra (gate scales folded into weights: i,f,o: -log2e,
// g: 2*log2e):
//   c' = (c*P + (Eg-1)(1+Ef)) * rcp(P*(1+Ef)),  P = (1+Ei)(Eg+1)
//   h  = (Ec-1) * rcp((1+Eo)(Ec+1)),            Ec = 2^(2*log2e*c)
// => 5 exp + 2 rcp per (row,unit).

#define B_ 4096
#define T_ 200

typedef _Float16 half8 __attribute__((ext_vector_type(8)));
typedef float f32x4 __attribute__((ext_vector_type(4)));

#define K1f 1.4426950408889634f   // log2(e)
#define K2f 2.8853900817779268f   // 2*log2(e)

__global__ __launch_bounds__(512) void lstm_kernel(
    const float* __restrict__ x,     // [4096][200][2]
    const float* __restrict__ W_ih,  // [256][2]
    const float* __restrict__ W_hh,  // [256][64]
    const float* __restrict__ b_ih,  // [256]
    const float* __restrict__ b_hh,  // [256]
    const float* __restrict__ W_fc,  // [2][64]
    const float* __restrict__ b_fc,  // [2]
    float* __restrict__ out)         // [4096][2]
{
    __shared__ float xs[16][404];           // x tile (float4-aligned; cols 400..403 pad)
    __shared__ _Float16 hsh[2][2][8][72];   // [group][buf][local row][unit]
    __shared__ float wfc[130];              // W_fc (128) + b_fc (2)
    __shared__ int ctr[2];                  // per-group generation counters

    const int tid  = threadIdx.x;
    const int lane = tid & 63;
    const int w    = tid >> 6;      // wave 0..7
    const int wq   = w & 3;         // unit quadrant
    const int grp  = w >> 2;        // group: 0 = rows 0-7, 1 = rows 8-15
    const int c    = lane & 15;
    const int g    = lane >> 4;
    const int r0   = blockIdx.x * 16;

    // ---- stage x tile (coalesced float4): 16 rows x 100 float4 ----
    for (int i4 = tid; i4 < 1600; i4 += 512) {
        const int row = i4 / 100;
        const int j4  = i4 - row * 100;
        reinterpret_cast<float4*>(&xs[row][0])[j4] =
            reinterpret_cast<const float4*>(x + (size_t)(r0 + row) * 400)[j4];
    }
    // ---- zero hsh: 2*2*8*72 f16 = 2304 f16 = 1152 dwords ----
    for (int i = tid; i < 1152; i += 512)
        reinterpret_cast<unsigned int*>(&hsh[0][0][0][0])[i] = 0u;
    if (tid < 130) wfc[tid] = (tid < 128) ? W_fc[tid] : b_fc[tid - 128];
    if (tid < 2)   ctr[tid] = 0;

    // ---- W_hh B-fragments (f16, PRE-SCALED per gate) + x-proj coeffs ----
    // B-frag (16x16x32): lane l -> col = l&15 (=c), k = (l>>4)*8 + e
    half8 bfrag[4][2];
    float cw0[4], cw1[4], cbs[4];
    const int u = wq * 16 + c;             // hidden unit owned by this lane
    #pragma unroll
    for (int m = 0; m < 4; ++m) {          // gate: 0=i,1=f,2=g,3=o (PyTorch order)
        const float sc = (m == 2) ? K2f : -K1f;
        const int gr = m * 64 + u;
        cw0[m] = W_ih[gr * 2 + 0] * sc;
        cw1[m] = W_ih[gr * 2 + 1] * sc;
        cbs[m] = (b_ih[gr] + b_hh[gr]) * sc;
        #pragma unroll
        for (int kt = 0; kt < 2; ++kt) {
            const float* p = W_hh + gr * 64 + kt * 32 + g * 8;
            const float4 lo = reinterpret_cast<const float4*>(p)[0];
            const float4 hi = reinterpret_cast<const float4*>(p)[1];
            half8 f;
            f[0] = (_Float16)(lo.x * sc); f[1] = (_Float16)(lo.y * sc);
            f[2] = (_Float16)(lo.z * sc); f[3] = (_Float16)(lo.w * sc);
            f[4] = (_Float16)(hi.x * sc); f[5] = (_Float16)(hi.y * sc);
            f[6] = (_Float16)(hi.z * sc); f[7] = (_Float16)(hi.w * sc);
            bfrag[m][kt] = f;
        }
    }

    const int arow  = c >> 1;        // A'[p] = hG[p>>1]
    const int rowL  = 2 * g;         // first local row this lane activates
    const int gbase = 8 * grp;       // group's global row offset in xs
    const int g8    = g * 8;
    float cst0 = 0.f, cst1 = 0.f;

    __syncthreads();                 // one-time staging barrier

    // Phase-offset group B by ~512 cyc so the SIMD's two waves start staggered.
    if (grp == 1) __builtin_amdgcn_s_sleep(8);

    // One activation chain: pre-act args already exp2-scaled.
    #define ACT(p0_, p1_, p2_, p3_, cst, hvout)                                \
        {                                                                      \
            const float Ei = __builtin_amdgcn_exp2f(p0_);                      \
            const float Ef = __builtin_amdgcn_exp2f(p1_);                      \
            const float Eg = __builtin_amdgcn_exp2f(p2_);                      \
            const float Eo = __builtin_amdgcn_exp2f(p3_);                      \
            const float fEf = 1.0f + Ef;                                       \
            const float P   = (1.0f + Ei) * (Eg + 1.0f);                       \
            const float r1  = __builtin_amdgcn_rcpf(P * fEf);                  \
            cst = fmaf(cst, P, (Eg - 1.0f) * fEf) * r1;                        \
            const float Ec = __builtin_amdgcn_exp2f(fminf(K2f * cst, 60.0f));  \
            const float r2 = __builtin_amdgcn_rcpf((1.0f + Eo) * (Ec + 1.0f)); \
            hvout = (Ec - 1.0f) * r2;                                          \
        }

    for (int t = 0; t < T_; ++t) {
        const int rd = t & 1;
        // ---- top-of-step LDS reads (h + x), issued together ----
        const _Float16* hb = &hsh[grp][rd][0][0];
        const half8 a0 = *reinterpret_cast<const half8*>(hb + arow * 72 + g8);
        const half8 a1 = *reinterpret_cast<const half8*>(hb + arow * 72 + 32 + g8);
        const float2 xv0 = *reinterpret_cast<const float2*>(&xs[gbase + rowL][2 * t]);
        const float2 xv1 = *reinterpret_cast<const float2*>(&xs[gbase + rowL + 1][2 * t]);

        // ---- MFMA with proj folded into C ({p0,p0,p1,p1}) ----
        f32x4 acc[4];
        #pragma unroll
        for (int m = 0; m < 4; ++m) {
            const float p0 = fmaf(xv0.y, cw1[m], fmaf(xv0.x, cw0[m], cbs[m]));
            const float p1 = fmaf(xv1.y, cw1[m], fmaf(xv1.x, cw0[m], cbs[m]));
            f32x4 z = {p0, p0, p1, p1};
            z = __builtin_amdgcn_mfma_f32_16x16x32_f16(a0, bfrag[m][0], z, 0, 0, 0);
            z = __builtin_amdgcn_mfma_f32_16x16x32_f16(a1, bfrag[m][1], z, 0, 0, 0);
            acc[m] = z;
        }

        // ---- activations: STATIC regs 0 (row 2g) and 2 (row 2g+1) ----
        _Float16* hw = &hsh[grp][rd ^ 1][0][0];
        {
            float hv0, hv1;
            ACT(acc[0][0], acc[1][0], acc[2][0], acc[3][0], cst0, hv0);
            ACT(acc[0][2], acc[1][2], acc[2][2], acc[3][2], cst1, hv1);
            hw[rowL * 72 + u]       = (_Float16)hv0;
            hw[(rowL + 1) * 72 + u] = (_Float16)hv1;
        }

        // ---- per-group generation sync (no block barrier) ----
        __threadfence_block();           // drain own LDS writes
        if (lane == 0)
            __hip_atomic_fetch_add(&ctr[grp], 1, __ATOMIC_RELEASE,
                                   __HIP_MEMORY_SCOPE_WORKGROUP);
        const int target = 4 * (t + 1);
        while (__hip_atomic_load(&ctr[grp], __ATOMIC_ACQUIRE,
                                 __HIP_MEMORY_SCOPE_WORKGROUP) < target)
            __builtin_amdgcn_s_sleep(1);
    }

    __syncthreads();   // join both groups before the FC epilogue

    // ---- FC epilogue: h(199) is in buf 0 of each group ----
    if (tid < 32) {
        const int r = tid & 15;
        const int o = tid >> 4;
        const _Float16* hsrc = &hsh[r >> 3][0][r & 7][0];
        float s = wfc[128 + o];
        #pragma unroll
        for (int k = 0; k < 64; ++k)
            s = fmaf(wfc[o * 64 + k], (float)hsrc[k], s);
        out[(size_t)(r0 + r) * 2 + o] = s;
    }
}

extern "C" void kernel_launch(void* const* d_in, const int* in_sizes, int n_in,
                              void* d_out, int out_size, void* d_ws, size_t ws_size,
                              hipStream_t stream) {
    const float* x    = (const float*)d_in[0];
    const float* W_ih = (const float*)d_in[1];
    const float* W_hh = (const float*)d_in[2];
    const float* b_ih = (const float*)d_in[3];
    const float* b_hh = (const float*)d_in[4];
    const float* W_fc = (const float*)d_in[5];
    const float* b_fc = (const float*)d_in[6];
    float* out = (float*)d_out;

    lstm_kernel<<<B_ / 16, 512, 0, stream>>>(x, W_ih, W_hh, b_ih, b_hh, W_fc, b_fc, out);
}